// Round 9
// baseline (409.953 us; speedup 1.0000x reference)
//
#include <hip/hip_runtime.h>
#include <hip/hip_fp16.h>
#include <hip/hip_cooperative_groups.h>
#include <math.h>

namespace cg = cooperative_groups;

#define KK 25
#define H1C 32
#define H2C 64
#define FCC 128
#define NCLS 10
#define NG 64
#define M1 16      // nodes per block, layer-1
#define M2 10      // nodes per block, layer-2 (grid = 2000: single resident round)
#define TILEU 12800  // uints per 16-node xph tile: 25*16*64 halves / 2
#define PREPB 512    // cooperative prep grid (co-residency safe: ~1KB LDS, low VGPR)

typedef _Float16 v8h __attribute__((ext_vector_type(8)));
typedef _Float16 v4h __attribute__((ext_vector_type(4)));
typedef float v4f __attribute__((ext_vector_type(4)));

// ---------------- fused prep: zero + W2t + hist + scan + bucket --------------
// One cooperative kernel replaces {memset, deg, scan1, scan23, bucket}:
// 5 dispatch boundaries -> 4 grid syncs.
__global__ __launch_bounds__(256) void prep_kernel(
    const int* __restrict__ edge_index, int E, int N, int NB,
    int* __restrict__ degi,
    const float* __restrict__ W2, __half* __restrict__ W2t,
    const float* __restrict__ edge_attr,
    int* __restrict__ incl, int* __restrict__ bsum,
    int* __restrict__ rowst, int* __restrict__ cur,
    int4* __restrict__ es, float* __restrict__ gsum) {
    cg::grid_group grid = cg::this_grid();
    __shared__ int s[256];
    int tid = threadIdx.x;
    int gid = blockIdx.x * 256 + tid;
    const int stride = PREPB * 256;

    // ---- phase 0: zero degi+gsum, convert W2 -> fp16 transposed ----
    for (int i = gid; i < KK * H2C * H1C; i += stride) {
        int c = i & 31, o = (i >> 5) & 63, k = i >> 11;
        W2t[i] = __float2half(W2[(k * H1C + c) * H2C + o]);
    }
    for (int i = gid; i < N; i += stride) degi[i] = 0;
    for (int i = gid; i < NG * H2C; i += stride) gsum[i] = 0.0f;
    grid.sync();

    // ---- phase 1: degree histogram (global atomics, L2-resident) ----
    for (int e = gid; e < E; e += stride) atomicAdd(&degi[edge_index[E + e]], 1);
    grid.sync();

    // ---- phase 2a: per-block inclusive scan + raw block sums ----
    if ((int)blockIdx.x < NB) {
        int i = blockIdx.x * 256 + tid;
        int v = (i < N) ? degi[i] : 0;
        s[tid] = v;
        __syncthreads();
        for (int off = 1; off < 256; off <<= 1) {
            int t = (tid >= off) ? s[tid - off] : 0;
            __syncthreads();
            s[tid] += t;
            __syncthreads();
        }
        if (i < N) incl[i] = s[tid];
        if (tid == 255) bsum[blockIdx.x] = s[255];
    }
    grid.sync();

    // ---- phase 2b: each block derives its prefix from raw bsum ----
    if ((int)blockIdx.x < NB) {
        int lim = min(NB, (int)blockIdx.x);
        int v = 0;
        for (int j = tid; j < lim; j += 256) v += bsum[j];
        s[tid] = v;
        __syncthreads();
        for (int off = 1; off < 256; off <<= 1) {
            int t = (tid >= off) ? s[tid - off] : 0;
            __syncthreads();
            s[tid] += t;
            __syncthreads();
        }
        int prior = s[255];
        int i = blockIdx.x * 256 + tid;
        if (i < N) {
            int r = incl[i] - degi[i] + prior;
            rowst[i] = r;
            cur[i] = r;
        }
    }
    grid.sync();

    // ---- phase 3: bucket edges by dst; 16B packed {src, dst<<8|kbase, f0,f1} --
    for (int e = gid; e < E; e += stride) {
        float v0 = edge_attr[2 * e + 0] * 4.0f;
        float v1 = edge_attr[2 * e + 1] * 4.0f;
        int k0 = (int)floorf(v0); k0 = min(max(k0, 0), 3);
        int k1 = (int)floorf(v1); k1 = min(max(k1, 0), 3);
        float f0 = v0 - (float)k0, f1 = v1 - (float)k1;
        int dst = edge_index[E + e];
        int pos = atomicAdd(&cur[dst], 1);
        es[pos] = make_int4(edge_index[e], (dst << 8) | (k0 + 5 * k1),
                            __float_as_int(f0), __float_as_int(f1));
    }
}

// ---------------- layer 1 + fused xW2 MFMA -----------------------------------
// Phase A: CSR gather, register accumulate, boundary flush (proven path).
// Phase B: operand-swapped 16x16x32 MFMA; output staged in LDS and flushed as
// fully-coalesced 2048B tile stores (xph layout [n/16][25][16][64] fp16).
__global__ __launch_bounds__(256) void l1_kernel(
    const float* __restrict__ x,
    const int* __restrict__ rowst, const int* __restrict__ degi,
    const int4* __restrict__ es,
    const float* __restrict__ W1, const float* __restrict__ root1,
    const float* __restrict__ b1,
    const __half* __restrict__ W2t,   // [25][64][32] (c innermost)
    int N, int E,
    float* __restrict__ h1, __half* __restrict__ xph) {
    __shared__ float w1s[KK * H1C];
    __shared__ float agg1[M1 * H1C];
    __shared__ int4 eb[8][32];
    __shared__ float xb[8][32];
    __shared__ __half h1s[M1][H1C];       // fp16 h1 tile (MFMA B operand)
    __shared__ __half stg[5][M1][68];     // staging, 68 = 64 + 4 pad (banks)
    int tid = threadIdx.x;
    for (int i = tid; i < KK * H1C; i += 256) w1s[i] = W1[i];
    for (int i = tid; i < M1 * H1C; i += 256) agg1[i] = 0.0f;
    __syncthreads();
    int g = tid >> 5, o = tid & 31;
    int n0 = blockIdx.x * M1;
    int blkBeg = rowst[n0];
    int blkEnd = (n0 + M1 < N) ? rowst[n0 + M1] : E;
    int total = blkEnd - blkBeg;
    int per = (total + 7) >> 3;
    int wBeg = blkBeg + g * per;
    int wEnd = min(blkEnd, wBeg + per);
    int curDst = -1;
    float acc = 0.0f;
    for (int base = wBeg; base < wEnd; base += 32) {
        int m = min(32, wEnd - base);
        if (o < m) {
            int4 ed = es[base + o];
            eb[g][o] = ed;
            xb[g][o] = x[ed.x];
        }
        for (int j = 0; j < m; j++) {
            int4 ed = eb[g][j];
            float xs = xb[g][j];
            int dst = ed.y >> 8;
            if (dst != curDst) {
                if (curDst >= 0) atomicAdd(&agg1[(curDst - n0) * H1C + o], acc);
                acc = 0.0f;
                curDst = dst;
            }
            float f0 = __int_as_float(ed.z), f1 = __int_as_float(ed.w);
            float g0 = 1.0f - f0, g1 = 1.0f - f1;
            int kb = (ed.y & 0xff) << 5;
            float coef = g0 * g1 * w1s[kb + o] + f0 * g1 * w1s[kb + 32 + o] +
                         g0 * f1 * w1s[kb + 160 + o] + f0 * f1 * w1s[kb + 192 + o];
            acc = fmaf(xs, coef, acc);
        }
    }
    if (curDst >= 0) atomicAdd(&agg1[(curDst - n0) * H1C + o], acc);
    __syncthreads();
#pragma unroll
    for (int i = 0; i < 2; i++) {
        int ln = g + 8 * i;
        int n = n0 + ln;
        if (n < N) {
            float rdeg = 1.0f / fmaxf((float)degi[n], 1.0f);
            float hv = fmaxf(agg1[ln * H1C + o] * rdeg + x[n] * root1[o] + b1[o], 0.0f);
            h1[n * H1C + o] = hv;
            h1s[ln][o] = __float2half(hv);
        } else {
            h1s[ln][o] = __float2half(0.0f);
        }
    }
    __syncthreads();

    // ---- Phase B: xph tile [25][16][64] for this block's 16 nodes ----
    int w = tid >> 6, lane = tid & 63;
    int r15 = lane & 15, quad = lane >> 4;
    int o0 = w * 16;
    v8h bfrag = *(const v8h*)(&h1s[r15][quad * 8]);
    __half* xtile = xph + (size_t)blockIdx.x * (2 * TILEU);  // halves
    int cln = tid >> 4, coc = (tid & 15) * 4;                // copy mapping
    bool crow = (n0 + cln) < N;
    for (int kc = 0; kc < KK; kc += 5) {
#pragma unroll
        for (int kk = 0; kk < 5; kk++) {
            int k = kc + kk;
            v8h afrag = *(const v8h*)(W2t + ((k << 6) + o0 + r15) * H1C + quad * 8);
            v4f acc2 = {};
            acc2 = __builtin_amdgcn_mfma_f32_16x16x32_f16(afrag, bfrag, acc2, 0, 0, 0);
            v4h hv;
            hv[0] = (_Float16)acc2[0];
            hv[1] = (_Float16)acc2[1];
            hv[2] = (_Float16)acc2[2];
            hv[3] = (_Float16)acc2[3];
            *(v4h*)(&stg[kk][r15][o0 + quad * 4]) = hv;
        }
        __syncthreads();
#pragma unroll
        for (int kk = 0; kk < 5; kk++) {
            if (crow) {
                v4h hv = *(const v4h*)(&stg[kk][cln][coc]);
                // dest halves offset = (kc+kk)*1024 + tid*4  (fully coalesced)
                *(v4h*)(xtile + ((kc + kk) << 10) + (tid << 2)) = hv;
            }
        }
        __syncthreads();
    }
}

// ---------------- layer 2: half2-packed gather + segment accumulate ----------
__global__ __launch_bounds__(256) void l2_kernel(
    const float* __restrict__ h1,
    const int* __restrict__ rowst, const int* __restrict__ degi,
    const int4* __restrict__ es,
    const unsigned* __restrict__ xphu,  // [n/16][25][16][32] uints
    const float* __restrict__ root2, const float* __restrict__ b2,
    const int* __restrict__ batch,
    int N, int E, float* __restrict__ gsum) {
    __shared__ float agg[M2 * H2C];
    __shared__ int4 eb[4][64];
    int tid = threadIdx.x;
    for (int i = tid; i < M2 * H2C; i += 256) agg[i] = 0.0f;
    __syncthreads();
    int w = tid >> 6, lane = tid & 63;
    int o2 = lane & 31, eh = lane >> 5;
    int n0 = blockIdx.x * M2;
    int blkBeg = rowst[n0];
    int blkEnd = (n0 + M2 < N) ? rowst[n0 + M2] : E;
    int total = blkEnd - blkBeg;
    int per = (total + 3) >> 2;
    int wBeg = blkBeg + w * per;
    int wEnd = min(blkEnd, wBeg + per);
    int curDst = -1;
    float ax = 0.0f, ay = 0.0f;
    for (int base = wBeg; base < wEnd; base += 64) {
        int m = min(64, wEnd - base);
        if (lane < m) eb[w][lane] = es[base + lane];
        for (int j = 0; j < m; j += 2) {
            int jj = j + eh;
            bool act = jj < m;
            int4 ed = eb[w][act ? jj : j];
            const unsigned* p = xphu + (size_t)(ed.x >> 4) * TILEU +
                                ((ed.y & 0xff) << 9) + ((ed.x & 15) << 5) + o2;
            unsigned t0 = p[0], t1 = p[512], t2 = p[2560], t3 = p[3072];
            if (act) {
                int dst = ed.y >> 8;
                if (dst != curDst) {
                    if (curDst >= 0) {
                        atomicAdd(&agg[(curDst - n0) * H2C + 2 * o2], ax);
                        atomicAdd(&agg[(curDst - n0) * H2C + 2 * o2 + 1], ay);
                    }
                    ax = ay = 0.0f;
                    curDst = dst;
                }
                float f0 = __int_as_float(ed.z), f1 = __int_as_float(ed.w);
                float g0 = 1.0f - f0, g1 = 1.0f - f1;
                float b0 = g0 * g1, b1 = f0 * g1, bb2 = g0 * f1, b3 = f0 * f1;
                __half2 h0 = *(__half2*)&t0, h1v = *(__half2*)&t1;
                __half2 h2 = *(__half2*)&t2, h3 = *(__half2*)&t3;
                ax = fmaf(b0, __low2float(h0), ax);  ay = fmaf(b0, __high2float(h0), ay);
                ax = fmaf(b1, __low2float(h1v), ax); ay = fmaf(b1, __high2float(h1v), ay);
                ax = fmaf(bb2, __low2float(h2), ax); ay = fmaf(bb2, __high2float(h2), ay);
                ax = fmaf(b3, __low2float(h3), ax);  ay = fmaf(b3, __high2float(h3), ay);
            }
        }
    }
    if (curDst >= 0) {
        atomicAdd(&agg[(curDst - n0) * H2C + 2 * o2], ax);
        atomicAdd(&agg[(curDst - n0) * H2C + 2 * o2 + 1], ay);
    }
    __syncthreads();

    // epilogue: h2 = relu(agg/deg + h1@root2 + b2), in place in agg
#pragma unroll
    for (int i = 0; i < 3; i++) {
        int ln = w + 4 * i;
        int n = n0 + ln;
        if (ln < M2) {
            if (n < N) {
                float rd = 1.0f / fmaxf((float)degi[n], 1.0f);
                float v = agg[ln * H2C + lane] * rd + b2[lane];
                const float* hr = h1 + n * H1C;
#pragma unroll 8
                for (int c = 0; c < H1C; c++) v = fmaf(hr[c], root2[c * H2C + lane], v);
                agg[ln * H2C + lane] = fmaxf(v, 0.0f);
            } else {
                agg[ln * H2C + lane] = 0.0f;
            }
        }
    }
    __syncthreads();

    // pool: one atomic per (graph,o) per block
    if (tid < H2C) {
        float run = 0.0f;
        int curg = batch[n0];
        for (int ln = 0; ln < M2; ln++) {
            int n = n0 + ln;
            if (n >= N) break;
            int gg = batch[n];
            if (gg != curg) {
                atomicAdd(&gsum[curg * H2C + tid], run);
                run = 0.0f;
                curg = gg;
            }
            run += agg[ln * H2C + tid];
        }
        atomicAdd(&gsum[curg * H2C + tid], run);
    }
}

// ---------------- head: count via binary search, FC1+relu, FC2, log_softmax --
__global__ void head_kernel(const float* __restrict__ gsum,
                            const int* __restrict__ batch, int N,
                            const float* __restrict__ Wf1, const float* __restrict__ bf1,
                            const float* __restrict__ Wf2, const float* __restrict__ bf2,
                            float* __restrict__ out) {
    __shared__ float gc[H2C];
    __shared__ float t1[FCC];
    __shared__ float lg[NCLS];
    __shared__ float lse;
    __shared__ float scnt;
    int g = blockIdx.x, tid = threadIdx.x;
    if (tid == 0) {
        int lo = 0, hi = N;
        while (lo < hi) { int m = (lo + hi) >> 1; if (batch[m] < g) lo = m + 1; else hi = m; }
        int lb = lo;
        lo = 0; hi = N;
        while (lo < hi) { int m = (lo + hi) >> 1; if (batch[m] <= g) lo = m + 1; else hi = m; }
        scnt = (float)(lo - lb);
    }
    __syncthreads();
    if (tid < H2C) gc[tid] = gsum[g * H2C + tid] / fmaxf(scnt, 1.0f);
    __syncthreads();
    {
        float acc = bf1[tid];
        for (int c = 0; c < H2C; c++) acc += gc[c] * Wf1[c * FCC + tid];
        t1[tid] = fmaxf(acc, 0.0f);
    }
    __syncthreads();
    if (tid < NCLS) {
        float acc = bf2[tid];
        for (int j = 0; j < FCC; j++) acc += t1[j] * Wf2[j * NCLS + tid];
        lg[tid] = acc;
    }
    __syncthreads();
    if (tid == 0) {
        float m = lg[0];
        for (int c = 1; c < NCLS; c++) m = fmaxf(m, lg[c]);
        float s = 0.0f;
        for (int c = 0; c < NCLS; c++) s += expf(lg[c] - m);
        lse = m + logf(s);
    }
    __syncthreads();
    if (tid < NCLS) out[g * NCLS + tid] = lg[tid] - lse;
}

extern "C" void kernel_launch(void* const* d_in, const int* in_sizes, int n_in,
                              void* d_out, int out_size, void* d_ws, size_t ws_size,
                              hipStream_t stream) {
    const float* x          = (const float*)d_in[0];
    const float* edge_attr  = (const float*)d_in[1];
    const float* W1         = (const float*)d_in[2];
    const float* root1      = (const float*)d_in[3];
    const float* b1         = (const float*)d_in[4];
    const float* W2         = (const float*)d_in[5];
    const float* root2      = (const float*)d_in[6];
    const float* b2         = (const float*)d_in[7];
    const float* Wf1        = (const float*)d_in[8];
    const float* bf1        = (const float*)d_in[9];
    const float* Wf2        = (const float*)d_in[10];
    const float* bf2        = (const float*)d_in[11];
    const int*   edge_index = (const int*)d_in[12];
    const int*   batch      = (const int*)d_in[13];
    float* out = (float*)d_out;

    int N = in_sizes[13];       // 20000
    int E = in_sizes[12] / 2;   // 320000
    int NB = (N + 255) / 256;   // scan blocks
    const int NT1 = (N + M1 - 1) / M1;  // xph tiles

    // -------- workspace layout --------
    int4*     es   = (int4*)d_ws;                        // E packed sorted edges
    unsigned* xphu = (unsigned*)(es + E);                // NT1*TILEU uints, fp16 tiles
    __half*   w2t  = (__half*)(xphu + (size_t)NT1 * TILEU);  // 25*64*32 halves
    float* gsum  = (float*)(w2t + KK * H2C * H1C);       // NG*H2C  -- zeroed in prep
    int*   degi  = (int*)(gsum + NG * H2C);              // N       -- zeroed in prep
    int*   rowst = degi + N;                             // N
    int*   cur   = rowst + N;                            // N
    int*   incl  = cur + N;                              // N
    int*   bsum  = incl + N;                             // 256
    float* h1    = (float*)(bsum + 256);                 // N*H1C

    // fused prep: zero + W2t + hist + scan + bucket (cooperative, 1 dispatch)
    {
        const int*   ei_p  = edge_index;
        const float* W2_p  = W2;
        __half*      w2t_p = w2t;
        const float* ea_p  = edge_attr;
        void* args[] = {
            (void*)&ei_p, (void*)&E, (void*)&N, (void*)&NB,
            (void*)&degi, (void*)&W2_p, (void*)&w2t_p, (void*)&ea_p,
            (void*)&incl, (void*)&bsum, (void*)&rowst, (void*)&cur,
            (void*)&es, (void*)&gsum
        };
        hipLaunchCooperativeKernel((const void*)prep_kernel, dim3(PREPB), dim3(256),
                                   args, 0, stream);
    }

    l1_kernel<<<NT1, 256, 0, stream>>>(
        x, rowst, degi, es, W1, root1, b1, w2t, N, E, h1, (__half*)xphu);

    l2_kernel<<<(N + M2 - 1) / M2, 256, 0, stream>>>(
        h1, rowst, degi, es, xphu, root2, b2, batch, N, E, gsum);

    head_kernel<<<NG, FCC, 0, stream>>>(gsum, batch, N, Wf1, bf1, Wf2, bf2, out);
}

// Round 10
// 203.426 us; speedup vs baseline: 2.0152x; 2.0152x over previous
//
#include <hip/hip_runtime.h>
#include <hip/hip_fp16.h>
#include <math.h>

#define KK 25
#define H1C 32
#define H2C 64
#define FCC 128
#define NCLS 10
#define NG 64
#define M1 16      // nodes per block, layer-1
#define M2 10      // nodes per block, layer-2 (grid = 2000: single resident round)
#define TILEU 12800  // uints per 16-node xph tile: 25*16*64 halves / 2

typedef _Float16 v8h __attribute__((ext_vector_type(8)));
typedef _Float16 v4h __attribute__((ext_vector_type(4)));
typedef float v4f __attribute__((ext_vector_type(4)));

// ---------------- degree via global atomics (L2-resident counters) ----------
// Also folds in the tiny W2 -> fp16 transposed [25][64][32] conversion.
__global__ __launch_bounds__(256) void deg_kernel(
    const int* __restrict__ edge_index, int E,
    int* __restrict__ degi,
    const float* __restrict__ W2, __half* __restrict__ W2t) {
    int i = blockIdx.x * 256 + threadIdx.x;
    if (i < KK * H2C * H1C) {
        int c = i & 31, o = (i >> 5) & 63, k = i >> 11;
        W2t[i] = __float2half(W2[(k * H1C + c) * H2C + o]);
    }
    if (i < E) atomicAdd(&degi[edge_index[E + i]], 1);
}

// ---------------- scan1: per-block inclusive scan + raw block sums -----------
__global__ void scan1_kernel(const int* __restrict__ degi, int N,
                             int* __restrict__ incl, int* __restrict__ bsum) {
    __shared__ int s[256];
    int tid = threadIdx.x;
    int i = blockIdx.x * 256 + tid;
    int v = (i < N) ? degi[i] : 0;
    s[tid] = v;
    __syncthreads();
    for (int off = 1; off < 256; off <<= 1) {
        int t = (tid >= off) ? s[tid - off] : 0;
        __syncthreads();
        s[tid] += t;
        __syncthreads();
    }
    if (i < N) incl[i] = s[tid];
    if (tid == 255) bsum[blockIdx.x] = s[255];
}

// ---------------- scan23: each block derives its own prefix from raw bsum ----
__global__ void scan23_kernel(const int* __restrict__ incl, const int* __restrict__ degi,
                              const int* __restrict__ bsum, int nb, int N,
                              int* __restrict__ rowst, int* __restrict__ cur) {
    __shared__ int s[256];
    int tid = threadIdx.x;
    int lim = min(nb, (int)blockIdx.x);
    int v = 0;
    for (int j = tid; j < lim; j += 256) v += bsum[j];
    s[tid] = v;
    __syncthreads();
    for (int off = 1; off < 256; off <<= 1) {
        int t = (tid >= off) ? s[tid - off] : 0;
        __syncthreads();
        s[tid] += t;
        __syncthreads();
    }
    int prior = s[255];
    int i = blockIdx.x * 256 + tid;
    if (i < N) {
        int r = incl[i] - degi[i] + prior;
        rowst[i] = r;
        cur[i] = r;
    }
}

// ---------------- bucket edges by dst; 16B packed {src, dst<<8|kbase, f0, f1} --
__global__ void bucket_kernel(const float* __restrict__ edge_attr,
                              const int* __restrict__ edge_index, int E,
                              int* __restrict__ cur, int4* __restrict__ es) {
    int e = blockIdx.x * blockDim.x + threadIdx.x;
    if (e >= E) return;
    float v0 = edge_attr[2 * e + 0] * 4.0f;
    float v1 = edge_attr[2 * e + 1] * 4.0f;
    int k0 = (int)floorf(v0); k0 = min(max(k0, 0), 3);
    int k1 = (int)floorf(v1); k1 = min(max(k1, 0), 3);
    float f0 = v0 - (float)k0, f1 = v1 - (float)k1;
    int dst = edge_index[E + e];
    int pos = atomicAdd(&cur[dst], 1);
    es[pos] = make_int4(edge_index[e], (dst << 8) | (k0 + 5 * k1),
                        __float_as_int(f0), __float_as_int(f1));
}

// ---------------- layer 1 + fused xW2 MFMA -----------------------------------
// Phase A: CSR gather, register accumulate, boundary flush (proven path).
// Phase B: operand-swapped 16x16x32 MFMA; output staged in LDS and flushed as
// fully-coalesced 2048B tile stores (xph layout [n/16][25][16][64] fp16).
__global__ __launch_bounds__(256) void l1_kernel(
    const float* __restrict__ x,
    const int* __restrict__ rowst, const int* __restrict__ degi,
    const int4* __restrict__ es,
    const float* __restrict__ W1, const float* __restrict__ root1,
    const float* __restrict__ b1,
    const __half* __restrict__ W2t,   // [25][64][32] (c innermost)
    int N, int E,
    float* __restrict__ h1, __half* __restrict__ xph) {
    __shared__ float w1s[KK * H1C];
    __shared__ float agg1[M1 * H1C];
    __shared__ int4 eb[8][32];
    __shared__ float xb[8][32];
    __shared__ __half h1s[M1][H1C];       // fp16 h1 tile (MFMA B operand)
    __shared__ __half stg[5][M1][68];     // staging, 68 = 64 + 4 pad (banks)
    int tid = threadIdx.x;
    for (int i = tid; i < KK * H1C; i += 256) w1s[i] = W1[i];
    for (int i = tid; i < M1 * H1C; i += 256) agg1[i] = 0.0f;
    __syncthreads();
    int g = tid >> 5, o = tid & 31;
    int n0 = blockIdx.x * M1;
    int blkBeg = rowst[n0];
    int blkEnd = (n0 + M1 < N) ? rowst[n0 + M1] : E;
    int total = blkEnd - blkBeg;
    int per = (total + 7) >> 3;
    int wBeg = blkBeg + g * per;
    int wEnd = min(blkEnd, wBeg + per);
    int curDst = -1;
    float acc = 0.0f;
    for (int base = wBeg; base < wEnd; base += 32) {
        int m = min(32, wEnd - base);
        if (o < m) {
            int4 ed = es[base + o];
            eb[g][o] = ed;
            xb[g][o] = x[ed.x];
        }
        for (int j = 0; j < m; j++) {
            int4 ed = eb[g][j];
            float xs = xb[g][j];
            int dst = ed.y >> 8;
            if (dst != curDst) {
                if (curDst >= 0) atomicAdd(&agg1[(curDst - n0) * H1C + o], acc);
                acc = 0.0f;
                curDst = dst;
            }
            float f0 = __int_as_float(ed.z), f1 = __int_as_float(ed.w);
            float g0 = 1.0f - f0, g1 = 1.0f - f1;
            int kb = (ed.y & 0xff) << 5;
            float coef = g0 * g1 * w1s[kb + o] + f0 * g1 * w1s[kb + 32 + o] +
                         g0 * f1 * w1s[kb + 160 + o] + f0 * f1 * w1s[kb + 192 + o];
            acc = fmaf(xs, coef, acc);
        }
    }
    if (curDst >= 0) atomicAdd(&agg1[(curDst - n0) * H1C + o], acc);
    __syncthreads();
#pragma unroll
    for (int i = 0; i < 2; i++) {
        int ln = g + 8 * i;
        int n = n0 + ln;
        if (n < N) {
            float rdeg = 1.0f / fmaxf((float)degi[n], 1.0f);
            float hv = fmaxf(agg1[ln * H1C + o] * rdeg + x[n] * root1[o] + b1[o], 0.0f);
            h1[n * H1C + o] = hv;
            h1s[ln][o] = __float2half(hv);
        } else {
            h1s[ln][o] = __float2half(0.0f);
        }
    }
    __syncthreads();

    // ---- Phase B: xph tile [25][16][64] for this block's 16 nodes ----
    int w = tid >> 6, lane = tid & 63;
    int r15 = lane & 15, quad = lane >> 4;
    int o0 = w * 16;
    v8h bfrag = *(const v8h*)(&h1s[r15][quad * 8]);
    __half* xtile = xph + (size_t)blockIdx.x * (2 * TILEU);  // halves
    int cln = tid >> 4, coc = (tid & 15) * 4;                // copy mapping
    bool crow = (n0 + cln) < N;
    for (int kc = 0; kc < KK; kc += 5) {
#pragma unroll
        for (int kk = 0; kk < 5; kk++) {
            int k = kc + kk;
            v8h afrag = *(const v8h*)(W2t + ((k << 6) + o0 + r15) * H1C + quad * 8);
            v4f acc2 = {};
            acc2 = __builtin_amdgcn_mfma_f32_16x16x32_f16(afrag, bfrag, acc2, 0, 0, 0);
            v4h hv;
            hv[0] = (_Float16)acc2[0];
            hv[1] = (_Float16)acc2[1];
            hv[2] = (_Float16)acc2[2];
            hv[3] = (_Float16)acc2[3];
            *(v4h*)(&stg[kk][r15][o0 + quad * 4]) = hv;
        }
        __syncthreads();
#pragma unroll
        for (int kk = 0; kk < 5; kk++) {
            if (crow) {
                v4h hv = *(const v4h*)(&stg[kk][cln][coc]);
                // dest halves offset = (kc+kk)*1024 + tid*4  (fully coalesced)
                *(v4h*)(xtile + ((kc + kk) << 10) + (tid << 2)) = hv;
            }
        }
        __syncthreads();
    }
}

// ---------------- layer 2: 4-edges-per-wave-iter gather + segment accumulate -
// Each 16-lane group owns one edge (4 channels/lane via uint2 taps): doubles
// in-flight loads per wave vs the 2-edge half-wave scheme (latency-bound fix).
__global__ __launch_bounds__(256) void l2_kernel(
    const float* __restrict__ h1,
    const int* __restrict__ rowst, const int* __restrict__ degi,
    const int4* __restrict__ es,
    const unsigned* __restrict__ xphu,  // [n/16][25][16][32] uints
    const float* __restrict__ root2, const float* __restrict__ b2,
    const int* __restrict__ batch,
    int N, int E, float* __restrict__ gsum) {
    __shared__ float agg[M2 * H2C];
    __shared__ int4 eb[4][64];
    int tid = threadIdx.x;
    for (int i = tid; i < M2 * H2C; i += 256) agg[i] = 0.0f;
    __syncthreads();
    int w = tid >> 6, lane = tid & 63;
    int o4 = lane & 15;        // channel-quad: channels 4*o4 .. 4*o4+3
    int eg = lane >> 4;        // edge slot 0..3 within wave-iter
    int n0 = blockIdx.x * M2;
    int blkBeg = rowst[n0];
    int blkEnd = (n0 + M2 < N) ? rowst[n0 + M2] : E;
    int total = blkEnd - blkBeg;
    int per = (total + 3) >> 2;
    int wBeg = blkBeg + w * per;
    int wEnd = min(blkEnd, wBeg + per);
    int curDst = -1;
    float a0 = 0.0f, a1 = 0.0f, a2 = 0.0f, a3 = 0.0f;
    for (int base = wBeg; base < wEnd; base += 64) {
        int m = min(64, wEnd - base);
        if (lane < m) eb[w][lane] = es[base + lane];
        for (int j = 0; j < m; j += 4) {
            int jj = j + eg;
            bool act = jj < m;
            int4 ed = eb[w][act ? jj : j];
            const uint2* p2 = (const uint2*)(xphu + (size_t)(ed.x >> 4) * TILEU +
                                ((ed.y & 0xff) << 9) + ((ed.x & 15) << 5)) + o4;
            uint2 q0 = p2[0], q1 = p2[256], q2 = p2[1280], q3 = p2[1536];
            if (act) {
                int dst = ed.y >> 8;
                if (dst != curDst) {
                    if (curDst >= 0) {
                        float* ag = &agg[(curDst - n0) * H2C + (o4 << 2)];
                        atomicAdd(ag + 0, a0); atomicAdd(ag + 1, a1);
                        atomicAdd(ag + 2, a2); atomicAdd(ag + 3, a3);
                    }
                    a0 = a1 = a2 = a3 = 0.0f;
                    curDst = dst;
                }
                float f0 = __int_as_float(ed.z), f1 = __int_as_float(ed.w);
                float g0 = 1.0f - f0, g1 = 1.0f - f1;
                float b0 = g0 * g1, b1 = f0 * g1, bb2 = g0 * f1, b3 = f0 * f1;
                __half2 h00 = *(__half2*)&q0.x, h01 = *(__half2*)&q0.y;
                __half2 h10 = *(__half2*)&q1.x, h11 = *(__half2*)&q1.y;
                __half2 h20 = *(__half2*)&q2.x, h21 = *(__half2*)&q2.y;
                __half2 h30 = *(__half2*)&q3.x, h31 = *(__half2*)&q3.y;
                a0 = fmaf(b0, __low2float(h00), a0);  a1 = fmaf(b0, __high2float(h00), a1);
                a2 = fmaf(b0, __low2float(h01), a2);  a3 = fmaf(b0, __high2float(h01), a3);
                a0 = fmaf(b1, __low2float(h10), a0);  a1 = fmaf(b1, __high2float(h10), a1);
                a2 = fmaf(b1, __low2float(h11), a2);  a3 = fmaf(b1, __high2float(h11), a3);
                a0 = fmaf(bb2, __low2float(h20), a0); a1 = fmaf(bb2, __high2float(h20), a1);
                a2 = fmaf(bb2, __low2float(h21), a2); a3 = fmaf(bb2, __high2float(h21), a3);
                a0 = fmaf(b3, __low2float(h30), a0);  a1 = fmaf(b3, __high2float(h30), a1);
                a2 = fmaf(b3, __low2float(h31), a2);  a3 = fmaf(b3, __high2float(h31), a3);
            }
        }
    }
    if (curDst >= 0) {
        float* ag = &agg[(curDst - n0) * H2C + (o4 << 2)];
        atomicAdd(ag + 0, a0); atomicAdd(ag + 1, a1);
        atomicAdd(ag + 2, a2); atomicAdd(ag + 3, a3);
    }
    __syncthreads();

    // epilogue: h2 = relu(agg/deg + h1@root2 + b2), in place in agg
#pragma unroll
    for (int i = 0; i < 3; i++) {
        int ln = w + 4 * i;
        int n = n0 + ln;
        if (ln < M2) {
            if (n < N) {
                float rd = 1.0f / fmaxf((float)degi[n], 1.0f);
                float v = agg[ln * H2C + lane] * rd + b2[lane];
                const float* hr = h1 + n * H1C;
#pragma unroll 8
                for (int c = 0; c < H1C; c++) v = fmaf(hr[c], root2[c * H2C + lane], v);
                agg[ln * H2C + lane] = fmaxf(v, 0.0f);
            } else {
                agg[ln * H2C + lane] = 0.0f;
            }
        }
    }
    __syncthreads();

    // pool: one atomic per (graph,o) per block
    if (tid < H2C) {
        float run = 0.0f;
        int curg = batch[n0];
        for (int ln = 0; ln < M2; ln++) {
            int n = n0 + ln;
            if (n >= N) break;
            int gg = batch[n];
            if (gg != curg) {
                atomicAdd(&gsum[curg * H2C + tid], run);
                run = 0.0f;
                curg = gg;
            }
            run += agg[ln * H2C + tid];
        }
        atomicAdd(&gsum[curg * H2C + tid], run);
    }
}

// ---------------- head: count via binary search, FC1+relu, FC2, log_softmax --
__global__ void head_kernel(const float* __restrict__ gsum,
                            const int* __restrict__ batch, int N,
                            const float* __restrict__ Wf1, const float* __restrict__ bf1,
                            const float* __restrict__ Wf2, const float* __restrict__ bf2,
                            float* __restrict__ out) {
    __shared__ float gc[H2C];
    __shared__ float t1[FCC];
    __shared__ float lg[NCLS];
    __shared__ float lse;
    __shared__ float scnt;
    int g = blockIdx.x, tid = threadIdx.x;
    if (tid == 0) {
        int lo = 0, hi = N;
        while (lo < hi) { int m = (lo + hi) >> 1; if (batch[m] < g) lo = m + 1; else hi = m; }
        int lb = lo;
        lo = 0; hi = N;
        while (lo < hi) { int m = (lo + hi) >> 1; if (batch[m] <= g) lo = m + 1; else hi = m; }
        scnt = (float)(lo - lb);
    }
    __syncthreads();
    if (tid < H2C) gc[tid] = gsum[g * H2C + tid] / fmaxf(scnt, 1.0f);
    __syncthreads();
    {
        float acc = bf1[tid];
        for (int c = 0; c < H2C; c++) acc += gc[c] * Wf1[c * FCC + tid];
        t1[tid] = fmaxf(acc, 0.0f);
    }
    __syncthreads();
    if (tid < NCLS) {
        float acc = bf2[tid];
        for (int j = 0; j < FCC; j++) acc += t1[j] * Wf2[j * NCLS + tid];
        lg[tid] = acc;
    }
    __syncthreads();
    if (tid == 0) {
        float m = lg[0];
        for (int c = 1; c < NCLS; c++) m = fmaxf(m, lg[c]);
        float s = 0.0f;
        for (int c = 0; c < NCLS; c++) s += expf(lg[c] - m);
        lse = m + logf(s);
    }
    __syncthreads();
    if (tid < NCLS) out[g * NCLS + tid] = lg[tid] - lse;
}

extern "C" void kernel_launch(void* const* d_in, const int* in_sizes, int n_in,
                              void* d_out, int out_size, void* d_ws, size_t ws_size,
                              hipStream_t stream) {
    const float* x          = (const float*)d_in[0];
    const float* edge_attr  = (const float*)d_in[1];
    const float* W1         = (const float*)d_in[2];
    const float* root1      = (const float*)d_in[3];
    const float* b1         = (const float*)d_in[4];
    const float* W2         = (const float*)d_in[5];
    const float* root2      = (const float*)d_in[6];
    const float* b2         = (const float*)d_in[7];
    const float* Wf1        = (const float*)d_in[8];
    const float* bf1        = (const float*)d_in[9];
    const float* Wf2        = (const float*)d_in[10];
    const float* bf2        = (const float*)d_in[11];
    const int*   edge_index = (const int*)d_in[12];
    const int*   batch      = (const int*)d_in[13];
    float* out = (float*)d_out;

    const int N = in_sizes[13];       // 20000
    const int E = in_sizes[12] / 2;   // 320000
    const int NB = (N + 255) / 256;   // scan blocks
    const int NT1 = (N + M1 - 1) / M1;  // xph tiles

    // -------- workspace layout --------
    int4*     es   = (int4*)d_ws;                        // E packed sorted edges
    unsigned* xphu = (unsigned*)(es + E);                // NT1*TILEU uints, fp16 tiles
    __half*   w2t  = (__half*)(xphu + (size_t)NT1 * TILEU);  // 25*64*32 halves
    float* gsum  = (float*)(w2t + KK * H2C * H1C);       // NG*H2C  -- zeroed
    int*   degi  = (int*)(gsum + NG * H2C);              // N       -- zeroed (same memset)
    int*   rowst = degi + N;                             // N
    int*   cur   = rowst + N;                            // N
    int*   incl  = cur + N;                              // N
    int*   bsum  = incl + N;                             // 256
    float* h1    = (float*)(bsum + 256);                 // N*H1C

    // single memset covers gsum (NG*H2C floats) + degi (N ints), adjacent
    hipMemsetAsync(gsum, 0, (size_t)NG * H2C * sizeof(float) + (size_t)N * sizeof(int),
                   stream);

    int degBlocks = (E + 255) / 256;
    deg_kernel<<<degBlocks, 256, 0, stream>>>(edge_index, E, degi, W2, w2t);

    scan1_kernel<<<NB, 256, 0, stream>>>(degi, N, incl, bsum);
    scan23_kernel<<<NB, 256, 0, stream>>>(incl, degi, bsum, NB, N, rowst, cur);

    bucket_kernel<<<(E + 255) / 256, 256, 0, stream>>>(edge_attr, edge_index, E, cur, es);

    l1_kernel<<<NT1, 256, 0, stream>>>(
        x, rowst, degi, es, W1, root1, b1, w2t, N, E, h1, (__half*)xphu);

    l2_kernel<<<(N + M2 - 1) / M2, 256, 0, stream>>>(
        h1, rowst, degi, es, xphu, root2, b2, batch, N, E, gsum);

    head_kernel<<<NG, FCC, 0, stream>>>(gsum, batch, N, Wf1, bf1, Wf2, bf2, out);
}

// Round 11
// 194.940 us; speedup vs baseline: 2.1030x; 1.0435x over previous
//
#include <hip/hip_runtime.h>
#include <hip/hip_fp16.h>
#include <math.h>

#define KK 25
#define H1C 32
#define H2C 64
#define FCC 128
#define NCLS 10
#define NG 64
#define M1 16      // nodes per block, layer-1 (locked: 16x16 MFMA tile)
#define M2 10      // nodes per block, layer-2 (grid = 2000: single resident round)
#define TILEU 12800  // uints per 16-node xph tile: 25*16*64 halves / 2

typedef _Float16 v8h __attribute__((ext_vector_type(8)));
typedef _Float16 v4h __attribute__((ext_vector_type(4)));
typedef float v4f __attribute__((ext_vector_type(4)));

// ---------------- degree via global atomics (L2-resident counters) ----------
// Also folds in the tiny W2 -> fp16 transposed [25][64][32] conversion.
__global__ __launch_bounds__(256) void deg_kernel(
    const int* __restrict__ edge_index, int E,
    int* __restrict__ degi,
    const float* __restrict__ W2, __half* __restrict__ W2t) {
    int i = blockIdx.x * 256 + threadIdx.x;
    if (i < KK * H2C * H1C) {
        int c = i & 31, o = (i >> 5) & 63, k = i >> 11;
        W2t[i] = __float2half(W2[(k * H1C + c) * H2C + o]);
    }
    if (i < E) atomicAdd(&degi[edge_index[E + i]], 1);
}

// ---------------- scan1: per-block inclusive scan + raw block sums -----------
__global__ void scan1_kernel(const int* __restrict__ degi, int N,
                             int* __restrict__ incl, int* __restrict__ bsum) {
    __shared__ int s[256];
    int tid = threadIdx.x;
    int i = blockIdx.x * 256 + tid;
    int v = (i < N) ? degi[i] : 0;
    s[tid] = v;
    __syncthreads();
    for (int off = 1; off < 256; off <<= 1) {
        int t = (tid >= off) ? s[tid - off] : 0;
        __syncthreads();
        s[tid] += t;
        __syncthreads();
    }
    if (i < N) incl[i] = s[tid];
    if (tid == 255) bsum[blockIdx.x] = s[255];
}

// ---------------- scan23: each block derives its own prefix from raw bsum ----
__global__ void scan23_kernel(const int* __restrict__ incl, const int* __restrict__ degi,
                              const int* __restrict__ bsum, int nb, int N,
                              int* __restrict__ rowst, int* __restrict__ cur) {
    __shared__ int s[256];
    int tid = threadIdx.x;
    int lim = min(nb, (int)blockIdx.x);
    int v = 0;
    for (int j = tid; j < lim; j += 256) v += bsum[j];
    s[tid] = v;
    __syncthreads();
    for (int off = 1; off < 256; off <<= 1) {
        int t = (tid >= off) ? s[tid - off] : 0;
        __syncthreads();
        s[tid] += t;
        __syncthreads();
    }
    int prior = s[255];
    int i = blockIdx.x * 256 + tid;
    if (i < N) {
        int r = incl[i] - degi[i] + prior;
        rowst[i] = r;
        cur[i] = r;
    }
}

// ---------------- bucket edges by dst; 16B packed {src, dst<<8|kbase, f0, f1} --
__global__ void bucket_kernel(const float* __restrict__ edge_attr,
                              const int* __restrict__ edge_index, int E,
                              int* __restrict__ cur, int4* __restrict__ es) {
    int e = blockIdx.x * blockDim.x + threadIdx.x;
    if (e >= E) return;
    float v0 = edge_attr[2 * e + 0] * 4.0f;
    float v1 = edge_attr[2 * e + 1] * 4.0f;
    int k0 = (int)floorf(v0); k0 = min(max(k0, 0), 3);
    int k1 = (int)floorf(v1); k1 = min(max(k1, 0), 3);
    float f0 = v0 - (float)k0, f1 = v1 - (float)k1;
    int dst = edge_index[E + e];
    int pos = atomicAdd(&cur[dst], 1);
    es[pos] = make_int4(edge_index[e], (dst << 8) | (k0 + 5 * k1),
                        __float_as_int(f0), __float_as_int(f1));
}

// ---------------- layer 1 + fused xW2 MFMA -----------------------------------
// Phase A: CSR gather, register accumulate, boundary flush (proven path).
// Phase B: operand-swapped 16x16x32 MFMA; output staged in LDS and flushed as
// fully-coalesced 2048B tile stores (xph layout [n/16][25][16][64] fp16).
__global__ __launch_bounds__(256) void l1_kernel(
    const float* __restrict__ x,
    const int* __restrict__ rowst, const int* __restrict__ degi,
    const int4* __restrict__ es,
    const float* __restrict__ W1, const float* __restrict__ root1,
    const float* __restrict__ b1,
    const __half* __restrict__ W2t,   // [25][64][32] (c innermost)
    int N, int E,
    float* __restrict__ h1, __half* __restrict__ xph) {
    __shared__ float w1s[KK * H1C];
    __shared__ float agg1[M1 * H1C];
    __shared__ int4 eb[8][32];
    __shared__ float xb[8][32];
    __shared__ __half h1s[M1][H1C];       // fp16 h1 tile (MFMA B operand)
    __shared__ __half stg[5][M1][68];     // staging, 68 = 64 + 4 pad (banks)
    int tid = threadIdx.x;
    for (int i = tid; i < KK * H1C; i += 256) w1s[i] = W1[i];
    for (int i = tid; i < M1 * H1C; i += 256) agg1[i] = 0.0f;
    __syncthreads();
    int g = tid >> 5, o = tid & 31;
    int n0 = blockIdx.x * M1;
    int blkBeg = rowst[n0];
    int blkEnd = (n0 + M1 < N) ? rowst[n0 + M1] : E;
    int total = blkEnd - blkBeg;
    int per = (total + 7) >> 3;
    int wBeg = blkBeg + g * per;
    int wEnd = min(blkEnd, wBeg + per);
    int curDst = -1;
    float acc = 0.0f;
    for (int base = wBeg; base < wEnd; base += 32) {
        int m = min(32, wEnd - base);
        if (o < m) {
            int4 ed = es[base + o];
            eb[g][o] = ed;
            xb[g][o] = x[ed.x];
        }
        for (int j = 0; j < m; j++) {
            int4 ed = eb[g][j];
            float xs = xb[g][j];
            int dst = ed.y >> 8;
            if (dst != curDst) {
                if (curDst >= 0) atomicAdd(&agg1[(curDst - n0) * H1C + o], acc);
                acc = 0.0f;
                curDst = dst;
            }
            float f0 = __int_as_float(ed.z), f1 = __int_as_float(ed.w);
            float g0 = 1.0f - f0, g1 = 1.0f - f1;
            int kb = (ed.y & 0xff) << 5;
            float coef = g0 * g1 * w1s[kb + o] + f0 * g1 * w1s[kb + 32 + o] +
                         g0 * f1 * w1s[kb + 160 + o] + f0 * f1 * w1s[kb + 192 + o];
            acc = fmaf(xs, coef, acc);
        }
    }
    if (curDst >= 0) atomicAdd(&agg1[(curDst - n0) * H1C + o], acc);
    __syncthreads();
#pragma unroll
    for (int i = 0; i < 2; i++) {
        int ln = g + 8 * i;
        int n = n0 + ln;
        if (n < N) {
            float rdeg = 1.0f / fmaxf((float)degi[n], 1.0f);
            float hv = fmaxf(agg1[ln * H1C + o] * rdeg + x[n] * root1[o] + b1[o], 0.0f);
            h1[n * H1C + o] = hv;
            h1s[ln][o] = __float2half(hv);
        } else {
            h1s[ln][o] = __float2half(0.0f);
        }
    }
    __syncthreads();

    // ---- Phase B: xph tile [25][16][64] for this block's 16 nodes ----
    int w = tid >> 6, lane = tid & 63;
    int r15 = lane & 15, quad = lane >> 4;
    int o0 = w * 16;
    v8h bfrag = *(const v8h*)(&h1s[r15][quad * 8]);
    __half* xtile = xph + (size_t)blockIdx.x * (2 * TILEU);  // halves
    int cln = tid >> 4, coc = (tid & 15) * 4;                // copy mapping
    bool crow = (n0 + cln) < N;
    for (int kc = 0; kc < KK; kc += 5) {
#pragma unroll
        for (int kk = 0; kk < 5; kk++) {
            int k = kc + kk;
            v8h afrag = *(const v8h*)(W2t + ((k << 6) + o0 + r15) * H1C + quad * 8);
            v4f acc2 = {};
            acc2 = __builtin_amdgcn_mfma_f32_16x16x32_f16(afrag, bfrag, acc2, 0, 0, 0);
            v4h hv;
            hv[0] = (_Float16)acc2[0];
            hv[1] = (_Float16)acc2[1];
            hv[2] = (_Float16)acc2[2];
            hv[3] = (_Float16)acc2[3];
            *(v4h*)(&stg[kk][r15][o0 + quad * 4]) = hv;
        }
        __syncthreads();
#pragma unroll
        for (int kk = 0; kk < 5; kk++) {
            if (crow) {
                v4h hv = *(const v4h*)(&stg[kk][cln][coc]);
                // dest halves offset = (kc+kk)*1024 + tid*4  (fully coalesced)
                *(v4h*)(xtile + ((kc + kk) << 10) + (tid << 2)) = hv;
            }
        }
        __syncthreads();
    }
}

// ---------------- layer 2: half2-packed gather + segment accumulate ----------
__global__ __launch_bounds__(256) void l2_kernel(
    const float* __restrict__ h1,
    const int* __restrict__ rowst, const int* __restrict__ degi,
    const int4* __restrict__ es,
    const unsigned* __restrict__ xphu,  // [n/16][25][16][32] uints
    const float* __restrict__ root2, const float* __restrict__ b2,
    const int* __restrict__ batch,
    int N, int E, float* __restrict__ gsum) {
    __shared__ float agg[M2 * H2C];
    __shared__ int4 eb[4][64];
    int tid = threadIdx.x;
    for (int i = tid; i < M2 * H2C; i += 256) agg[i] = 0.0f;
    __syncthreads();
    int w = tid >> 6, lane = tid & 63;
    int o2 = lane & 31, eh = lane >> 5;
    int n0 = blockIdx.x * M2;
    int blkBeg = rowst[n0];
    int blkEnd = (n0 + M2 < N) ? rowst[n0 + M2] : E;
    int total = blkEnd - blkBeg;
    int per = (total + 3) >> 2;
    int wBeg = blkBeg + w * per;
    int wEnd = min(blkEnd, wBeg + per);
    int curDst = -1;
    float ax = 0.0f, ay = 0.0f;
    for (int base = wBeg; base < wEnd; base += 64) {
        int m = min(64, wEnd - base);
        if (lane < m) eb[w][lane] = es[base + lane];
        for (int j = 0; j < m; j += 2) {
            int jj = j + eh;
            bool act = jj < m;
            int4 ed = eb[w][act ? jj : j];
            const unsigned* p = xphu + (size_t)(ed.x >> 4) * TILEU +
                                ((ed.y & 0xff) << 9) + ((ed.x & 15) << 5) + o2;
            unsigned t0 = p[0], t1 = p[512], t2 = p[2560], t3 = p[3072];
            if (act) {
                int dst = ed.y >> 8;
                if (dst != curDst) {
                    if (curDst >= 0) {
                        atomicAdd(&agg[(curDst - n0) * H2C + 2 * o2], ax);
                        atomicAdd(&agg[(curDst - n0) * H2C + 2 * o2 + 1], ay);
                    }
                    ax = ay = 0.0f;
                    curDst = dst;
                }
                float f0 = __int_as_float(ed.z), f1 = __int_as_float(ed.w);
                float g0 = 1.0f - f0, g1 = 1.0f - f1;
                float b0 = g0 * g1, b1 = f0 * g1, bb2 = g0 * f1, b3 = f0 * f1;
                __half2 h0 = *(__half2*)&t0, h1v = *(__half2*)&t1;
                __half2 h2 = *(__half2*)&t2, h3 = *(__half2*)&t3;
                ax = fmaf(b0, __low2float(h0), ax);  ay = fmaf(b0, __high2float(h0), ay);
                ax = fmaf(b1, __low2float(h1v), ax); ay = fmaf(b1, __high2float(h1v), ay);
                ax = fmaf(bb2, __low2float(h2), ax); ay = fmaf(bb2, __high2float(h2), ay);
                ax = fmaf(b3, __low2float(h3), ax);  ay = fmaf(b3, __high2float(h3), ay);
            }
        }
    }
    if (curDst >= 0) {
        atomicAdd(&agg[(curDst - n0) * H2C + 2 * o2], ax);
        atomicAdd(&agg[(curDst - n0) * H2C + 2 * o2 + 1], ay);
    }
    __syncthreads();

    // epilogue: h2 = relu(agg/deg + h1@root2 + b2), in place in agg
#pragma unroll
    for (int i = 0; i < 3; i++) {
        int ln = w + 4 * i;
        int n = n0 + ln;
        if (ln < M2) {
            if (n < N) {
                float rd = 1.0f / fmaxf((float)degi[n], 1.0f);
                float v = agg[ln * H2C + lane] * rd + b2[lane];
                const float* hr = h1 + n * H1C;
#pragma unroll 8
                for (int c = 0; c < H1C; c++) v = fmaf(hr[c], root2[c * H2C + lane], v);
                agg[ln * H2C + lane] = fmaxf(v, 0.0f);
            } else {
                agg[ln * H2C + lane] = 0.0f;
            }
        }
    }
    __syncthreads();

    // pool: one atomic per (graph,o) per block
    if (tid < H2C) {
        float run = 0.0f;
        int curg = batch[n0];
        for (int ln = 0; ln < M2; ln++) {
            int n = n0 + ln;
            if (n >= N) break;
            int gg = batch[n];
            if (gg != curg) {
                atomicAdd(&gsum[curg * H2C + tid], run);
                run = 0.0f;
                curg = gg;
            }
            run += agg[ln * H2C + tid];
        }
        atomicAdd(&gsum[curg * H2C + tid], run);
    }
}

// ---------------- head: count via binary search, FC1+relu, FC2, log_softmax --
__global__ void head_kernel(const float* __restrict__ gsum,
                            const int* __restrict__ batch, int N,
                            const float* __restrict__ Wf1, const float* __restrict__ bf1,
                            const float* __restrict__ Wf2, const float* __restrict__ bf2,
                            float* __restrict__ out) {
    __shared__ float gc[H2C];
    __shared__ float t1[FCC];
    __shared__ float lg[NCLS];
    __shared__ float lse;
    __shared__ float scnt;
    int g = blockIdx.x, tid = threadIdx.x;
    if (tid == 0) {
        int lo = 0, hi = N;
        while (lo < hi) { int m = (lo + hi) >> 1; if (batch[m] < g) lo = m + 1; else hi = m; }
        int lb = lo;
        lo = 0; hi = N;
        while (lo < hi) { int m = (lo + hi) >> 1; if (batch[m] <= g) lo = m + 1; else hi = m; }
        scnt = (float)(lo - lb);
    }
    __syncthreads();
    if (tid < H2C) gc[tid] = gsum[g * H2C + tid] / fmaxf(scnt, 1.0f);
    __syncthreads();
    {
        float acc = bf1[tid];
        for (int c = 0; c < H2C; c++) acc += gc[c] * Wf1[c * FCC + tid];
        t1[tid] = fmaxf(acc, 0.0f);
    }
    __syncthreads();
    if (tid < NCLS) {
        float acc = bf2[tid];
        for (int j = 0; j < FCC; j++) acc += t1[j] * Wf2[j * NCLS + tid];
        lg[tid] = acc;
    }
    __syncthreads();
    if (tid == 0) {
        float m = lg[0];
        for (int c = 1; c < NCLS; c++) m = fmaxf(m, lg[c]);
        float s = 0.0f;
        for (int c = 0; c < NCLS; c++) s += expf(lg[c] - m);
        lse = m + logf(s);
    }
    __syncthreads();
    if (tid < NCLS) out[g * NCLS + tid] = lg[tid] - lse;
}

extern "C" void kernel_launch(void* const* d_in, const int* in_sizes, int n_in,
                              void* d_out, int out_size, void* d_ws, size_t ws_size,
                              hipStream_t stream) {
    const float* x          = (const float*)d_in[0];
    const float* edge_attr  = (const float*)d_in[1];
    const float* W1         = (const float*)d_in[2];
    const float* root1      = (const float*)d_in[3];
    const float* b1         = (const float*)d_in[4];
    const float* W2         = (const float*)d_in[5];
    const float* root2      = (const float*)d_in[6];
    const float* b2         = (const float*)d_in[7];
    const float* Wf1        = (const float*)d_in[8];
    const float* bf1        = (const float*)d_in[9];
    const float* Wf2        = (const float*)d_in[10];
    const float* bf2        = (const float*)d_in[11];
    const int*   edge_index = (const int*)d_in[12];
    const int*   batch      = (const int*)d_in[13];
    float* out = (float*)d_out;

    const int N = in_sizes[13];       // 20000
    const int E = in_sizes[12] / 2;   // 320000
    const int NB = (N + 255) / 256;   // scan blocks
    const int NT1 = (N + M1 - 1) / M1;  // xph tiles

    // -------- workspace layout --------
    int4*     es   = (int4*)d_ws;                        // E packed sorted edges
    unsigned* xphu = (unsigned*)(es + E);                // NT1*TILEU uints, fp16 tiles
    __half*   w2t  = (__half*)(xphu + (size_t)NT1 * TILEU);  // 25*64*32 halves
    float* gsum  = (float*)(w2t + KK * H2C * H1C);       // NG*H2C  -- zeroed
    int*   degi  = (int*)(gsum + NG * H2C);              // N       -- zeroed (same memset)
    int*   rowst = degi + N;                             // N
    int*   cur   = rowst + N;                            // N
    int*   incl  = cur + N;                              // N
    int*   bsum  = incl + N;                             // 256
    float* h1    = (float*)(bsum + 256);                 // N*H1C

    // single memset covers gsum (NG*H2C floats) + degi (N ints), adjacent
    hipMemsetAsync(gsum, 0, (size_t)NG * H2C * sizeof(float) + (size_t)N * sizeof(int),
                   stream);

    int degBlocks = (E + 255) / 256;
    deg_kernel<<<degBlocks, 256, 0, stream>>>(edge_index, E, degi, W2, w2t);

    scan1_kernel<<<NB, 256, 0, stream>>>(degi, N, incl, bsum);
    scan23_kernel<<<NB, 256, 0, stream>>>(incl, degi, bsum, NB, N, rowst, cur);

    bucket_kernel<<<(E + 255) / 256, 256, 0, stream>>>(edge_attr, edge_index, E, cur, es);

    l1_kernel<<<NT1, 256, 0, stream>>>(
        x, rowst, degi, es, W1, root1, b1, w2t, N, E, h1, (__half*)xphu);

    l2_kernel<<<(N + M2 - 1) / M2, 256, 0, stream>>>(
        h1, rowst, degi, es, xphu, root2, b2, batch, N, E, gsum);

    head_kernel<<<NG, FCC, 0, stream>>>(gsum, batch, N, Wf1, bf1, Wf2, bf2, out);
}